// Round 10
// baseline (225.855 us; speedup 1.0000x reference)
//
#include <hip/hip_runtime.h>

#define B_ 4
#define T_ 2048
#define D_ 1024
#define H_ 16
#define S_ 64

typedef __attribute__((ext_vector_type(8))) short bf16x8;
typedef __attribute__((ext_vector_type(16))) float f32x16;
typedef unsigned int uint;

__device__ __forceinline__ short f2bf(float f) {
    union { float f; uint u; } v; v.f = f;
    uint r = v.u + 0x7fffu + ((v.u >> 16) & 1u);   // RNE
    return (short)(r >> 16);
}

// async global->LDS, 16B per lane; LDS dst = wave-uniform base + lane*16
__device__ __forceinline__ void gld16(const short* g, short* l) {
    __builtin_amdgcn_global_load_lds((const __attribute__((address_space(1))) void*)g,
                                     (__attribute__((address_space(3))) void*)l, 16, 0, 0);
}

// ---------------- fused fp32->bf16 prepass: x, Wq, Wu ----------------
__global__ __launch_bounds__(256) void cvt3(const float* __restrict__ x,
                                            const float* __restrict__ wq,
                                            const float* __restrict__ wu,
                                            short* __restrict__ xb,
                                            short* __restrict__ wqb,
                                            short* __restrict__ wub) {
    const int NX = B_ * T_ * D_ / 8;   // 1048576 8-elem units
    const int NW = D_ * D_ / 8;        // 131072
    int i = blockIdx.x * 256 + threadIdx.x;
    const float* src; short* dst; int off;
    if (i < NX)            { src = x;  dst = xb;  off = i; }
    else if (i < NX + NW)  { src = wq; dst = wqb; off = i - NX; }
    else                   { src = wu; dst = wub; off = i - NX - NW; }
    float4 a = *(const float4*)(src + (size_t)off * 8);
    float4 b = *(const float4*)(src + (size_t)off * 8 + 4);
    short o[8] = {f2bf(a.x), f2bf(a.y), f2bf(a.z), f2bf(a.w),
                  f2bf(b.x), f2bf(b.y), f2bf(b.z), f2bf(b.w)};
    *(bf16x8*)(dst + (size_t)off * 8) = *(bf16x8*)o;
}

// ---------------- bf16 MFMA GEMM v9: reg-staged depth-2 pipeline (T14) ------
// C[M,N] = A[M,K] @ Bt[N,K]^T (+bias). 128x128 tile, 256 thr, 4 waves
// (2wm x 2wn, wave owns 64x64 = 2x2 f32x16 acc). BK=64, 2 LDS buffers.
// THE CHANGE vs r8: staging goes global->REG->LDS with depth 2 — loads for
// tile t+2 are issued at step t and ds-written at step t+1, so the
// top-of-loop vmcnt(0) waits on loads issued a FULL step (~4000cy) ago:
// the per-step latency drain (the r0..r8 invariant) disappears.
// Barrier structure == r8's proven single-barrier pattern:
//   vmcnt(0)+lgkmcnt(0) -> s_barrier -> WRITE(t+1) -> LOAD(t+2) -> COMPUTE(t)
// (wave X's compute(t) needs wave Y's write(t): Y's lgkm-drain precedes the
//  barrier, exactly as the DMA vmcnt did in r8.)
// Global reads are LINEAR row-coalesced (8 lanes x 128B rows); the XOR
// swizzle moves to the ds_write address -> LDS image bit-identical to r8.
#define LOADR(t) do {                                                             \
        const int kk_ = (t) << 6;                                                 \
        _Pragma("unroll")                                                         \
        for (int j_ = 0; j_ < 4; ++j_) {                                          \
            stA[j_] = *(const bf16x8*)(Ap + (size_t)(row0 + 32 * j_) * K + kk_ + c7 * 8); \
            stB[j_] = *(const bf16x8*)(Bp + (size_t)(row0 + 32 * j_) * K + kk_ + c7 * 8); \
        }                                                                         \
    } while (0)

#define WRITEL(bi) do {                                                           \
        _Pragma("unroll")                                                         \
        for (int j_ = 0; j_ < 4; ++j_) {                                          \
            const int r_ = row0 + 32 * j_;                                        \
            const int s_ = (r_ * 8 + (c7 ^ (r_ & 7))) * 8;                        \
            *(bf16x8*)&As[bi][s_] = stA[j_];                                      \
            *(bf16x8*)&Bs[bi][s_] = stB[j_];                                      \
        }                                                                         \
    } while (0)

template <bool OUT_BF16>
__global__ __launch_bounds__(256, 2) void gemm_bt(const short* __restrict__ A,
                                                  const short* __restrict__ Bt,
                                                  const float* __restrict__ bias,
                                                  void* __restrict__ Cv,
                                                  int M, int N, int K) {
    __shared__ short As[2][8192];   // 2 x 16 KB, row-major [128][64] bf16 (swizzled slots)
    __shared__ short Bs[2][8192];   // 2 x 16 KB
    const int tid  = threadIdx.x;
    const int lane = tid & 63;
    const int wv   = tid >> 6;       // 0..3
    const int wm   = wv >> 1;        // 0..1 -> 64-row strip
    const int wn   = wv & 1;         // 0..1 -> 64-col strip
    const int h32  = lane >> 5;
    const int row0 = tid >> 3;       // 0..31 (staging row within 32-row group)
    const int c7   = tid & 7;        // staging chunk

    // bijective XCD swizzle: each XCD owns nby/8 contiguous m-panels x all n.
    int bx = blockIdx.x, by = blockIdx.y;
    {
        const int nbx = gridDim.x, nby = gridDim.y;
        if ((nby & 7) == 0) {
            int f = blockIdx.x + nbx * blockIdx.y;
            int xcd = f & 7, slot = f >> 3;
            bx = slot % nbx;
            by = xcd * (nby >> 3) + slot / nbx;
        }
    }
    const int m0 = by * 128, n0 = bx * 128;
    const short* Ap = A + (size_t)m0 * K;
    const short* Bp = Bt + (size_t)n0 * K;

    f32x16 acc[2][2];
    #pragma unroll
    for (int i = 0; i < 2; ++i)
        #pragma unroll
        for (int j = 0; j < 2; ++j)
            #pragma unroll
            for (int r = 0; r < 16; ++r) acc[i][j][r] = 0.f;

    // fragment-read geometry (rows fixed per lane; slot varies by kk8)
    const int ra0 = wm * 64 + (lane & 31);    // A rows: ra0, ra0+32
    const int rb0 = wn * 64 + (lane & 31);    // B rows: rb0, rb0+32
    const int l7  = lane & 7;                 // == row&7 for all four rows

    bf16x8 stA[4], stB[4];
    const int nt = K >> 6;           // 16 K-steps (K=1024)

    // prologue: tile 0 -> regs -> buf0; issue tile-1 loads
    LOADR(0);
    asm volatile("s_waitcnt vmcnt(0)" ::: "memory");
    WRITEL(0);
    if (nt > 1) LOADR(1);
    __syncthreads();                 // one-time full drain; buf0 visible

    for (int t = 0; t < nt; ++t) {
        const int cur = t & 1;
        // regs(t+1) landed (issued a full step ago) + my writes(t) retired
        asm volatile("s_waitcnt vmcnt(0) lgkmcnt(0)" ::: "memory");
        __builtin_amdgcn_s_barrier();   // all waves: tile-t writes visible,
        asm volatile("" ::: "memory");  // reads of buf[cur^1] finished

        if (t + 1 < nt) WRITEL(cur ^ 1);   // tile t+1 regs -> other buffer
        if (t + 2 < nt) LOADR(t + 2);      // issue: a full step to land

        const short* Ab = As[cur];
        const short* Bb = Bs[cur];
        #pragma unroll
        for (int ks = 0; ks < 4; ++ks) {
            const int kk8 = ks * 2 + h32;
            const int sl  = (kk8 ^ l7) * 8;
            bf16x8 a0 = *(bf16x8*)&Ab[ra0 * 64 + sl];
            bf16x8 a1 = *(bf16x8*)&Ab[(ra0 + 32) * 64 + sl];
            bf16x8 b0 = *(bf16x8*)&Bb[rb0 * 64 + sl];
            bf16x8 b1 = *(bf16x8*)&Bb[(rb0 + 32) * 64 + sl];
            acc[0][0] = __builtin_amdgcn_mfma_f32_32x32x16_bf16(a0, b0, acc[0][0], 0, 0, 0);
            acc[0][1] = __builtin_amdgcn_mfma_f32_32x32x16_bf16(a0, b1, acc[0][1], 0, 0, 0);
            acc[1][0] = __builtin_amdgcn_mfma_f32_32x32x16_bf16(a1, b0, acc[1][0], 0, 0, 0);
            acc[1][1] = __builtin_amdgcn_mfma_f32_32x32x16_bf16(a1, b1, acc[1][1], 0, 0, 0);
        }
    }

    #pragma unroll
    for (int mt = 0; mt < 2; ++mt) {
        #pragma unroll
        for (int nt2 = 0; nt2 < 2; ++nt2) {
            const int rbase = m0 + wm * 64 + mt * 32;
            const int col   = n0 + wn * 64 + nt2 * 32 + (lane & 31);
            float bv = 0.f;
            if (!OUT_BF16 && bias) bv = bias[col];
            #pragma unroll
            for (int r = 0; r < 16; ++r) {
                int row = rbase + (r & 3) + 8 * (r >> 2) + 4 * h32;
                if constexpr (OUT_BF16)
                    ((short*)Cv)[(size_t)row * N + col] = f2bf(acc[mt][nt2][r]);
                else
                    ((float*)Cv)[(size_t)row * N + col] = acc[mt][nt2][r] + bv;
            }
        }
    }
}

// ---------------- MFMA attention v6 (byte-identical to round 8) -------------
__global__ __launch_bounds__(256, 3) void attn_mfma(const short* __restrict__ q,
                                                    short* __restrict__ o) {
    __shared__ short smem[20480];   // 40 KB: buf0=[0,10240), buf1=[10240,20480)
    const int tid  = threadIdx.x;
    const int lane = tid & 63;
    const int wv   = tid >> 6;
    const int h32  = lane >> 5;
    const int b  = blockIdx.y >> 4;
    const int hh = blockIdx.y & 15;
    const int t0 = blockIdx.x * 128;
    const short* qb = q + (size_t)b * (T_ * D_) + hh * S_;

    // tile-invariant staging geometry
    const int c8  = tid & 7;
    const int uu0 = tid >> 3;            // 0..31
    const int uu1 = uu0 + 32;            // 32..63
    const int u_0 = (uu0 & 0x33) | ((uu0 & 4) << 1) | ((uu0 & 8) >> 1);  // b2<->b3
    const int u_1 = (uu1 & 0x33) | ((uu1 & 4) << 1) | ((uu1 & 8) >> 1);
    const int kfo0 = (c8 * 64 + (u_0 ^ c8)) * 8;          // Kf within buffer
    const int kfo1 = (c8 * 64 + (u_1 ^ c8)) * 8;
    const int kto0 = 4096 + (u_0 >> 4) * 1536 + ((u_0 >> 2) & 1) * 768 + (c8 >> 2) * 8
                   + ((u_0 & 3) | (((u_0 >> 3) & 1) << 2)) + (c8 & 3) * 24;
    const int kto1 = 4096 + (u_1 >> 4) * 1536 + ((u_1 >> 2) & 1) * 768 + (c8 >> 2) * 8
                   + ((u_1 & 3) | (((u_1 >> 3) & 1) << 2)) + (c8 & 3) * 24;
    const short* g0 = qb + (size_t)u_0 * D_ + c8 * 8;
    const short* g1 = qb + (size_t)u_1 * D_ + c8 * 8;

    // ---- prologue: issue tile-0 loads, stage Q, read Q frags ----
    bf16x8 st0 = *(const bf16x8*)g0;            // tile 0 (u0 = 0)
    bf16x8 st1 = *(const bf16x8*)g1;
    #pragma unroll
    for (int rep = 0; rep < 4; ++rep) {
        int f = rep * 256 + tid;
        int r = f >> 3, cq = f & 7;
        bf16x8 v = *(const bf16x8*)(qb + (size_t)(t0 + r) * D_ + cq * 8);
        *(bf16x8*)&smem[(cq * 128 + (r ^ cq)) * 8] = v;
    }
    __syncthreads();
    bf16x8 Qreg[4];
    #pragma unroll
    for (int ks = 0; ks < 4; ++ks) {
        int kk8 = 2 * ks + h32;
        Qreg[ks] = *(bf16x8*)&smem[(kk8 * 128 + ((wv * 32 + (lane & 31)) ^ kk8)) * 8];
    }
    __syncthreads();                             // Q region (subset of buf0) free now
    // write tile 0 into buf0; issue tile-1 loads
    *(bf16x8*)&smem[kfo0] = st0;
    *(bf16x8*)&smem[kfo1] = st1;
    #pragma unroll
    for (int ds = 0; ds < 8; ++ds) {
        smem[kto0 + ds * 96] = st0[ds];
        smem[kto1 + ds * 96] = st1[ds];
    }
    st0 = *(const bf16x8*)(g0 + (size_t)64 * D_);
    st1 = *(const bf16x8*)(g1 + (size_t)64 * D_);

    f32x16 accO0, accO1;
    #pragma unroll
    for (int i = 0; i < 16; ++i) { accO0[i] = 0.f; accO1[i] = 0.f; }
    float lsp0 = 0.f, lsp1 = 0.f;
    const int prow = ((((lane & 7) << 2) | ((lane >> 3) & 3)) * 24) + h32 * 768;
    const float SCL = 0.18033688f;               // 0.125 * log2(e)

    int rb = 0;                                  // read-buffer base (shorts)
    for (int u0 = 0; u0 < T_; u0 += 64) {
        __syncthreads();          // everyone done with prev tile (other buffer)
        const int wb = 10240 - rb;

        // ---- S^T[64 keys x 32 t] = K Q^T  (from buf rb) ----
        f32x16 aS0, aS1;
        #pragma unroll
        for (int i = 0; i < 16; ++i) { aS0[i] = 0.f; aS1[i] = 0.f; }
        __builtin_amdgcn_s_setprio(1);
        #pragma unroll
        for (int ks = 0; ks < 4; ++ks) {
            int kk8 = 2 * ks + h32;
            bf16x8 k0 = *(bf16x8*)&smem[rb + (kk8 * 64 + ((lane & 31) ^ kk8)) * 8];
            bf16x8 k1 = *(bf16x8*)&smem[rb + (kk8 * 64 + ((32 + (lane & 31)) ^ kk8)) * 8];
            aS0 = __builtin_amdgcn_mfma_f32_32x32x16_bf16(k0, Qreg[ks], aS0, 0, 0, 0);
            aS1 = __builtin_amdgcn_mfma_f32_32x32x16_bf16(k1, Qreg[ks], aS1, 0, 0, 0);
        }
        __builtin_amdgcn_s_setprio(0);

        // ---- stage tile u0+64 into buf wb (regs loaded last iter) ----
        *(bf16x8*)&smem[wb + kfo0] = st0;
        *(bf16x8*)&smem[wb + kfo1] = st1;
        #pragma unroll
        for (int ds = 0; ds < 8; ++ds) {
            smem[wb + kto0 + ds * 96] = st0[ds];
            smem[wb + kto1 + ds * 96] = st1[ds];
        }
        // ---- issue loads for tile u0+128 (used next iteration) ----
        int un = u0 + 128; if (un >= T_) un = 0;   // tail: harmless dummy
        st0 = *(const bf16x8*)(g0 + (size_t)un * D_);
        st1 = *(const bf16x8*)(g1 + (size_t)un * D_);

        // ---- exp2; pack C-layout -> A-frags (overlaps the ds-writes above) ----
        bf16x8 af[4];
        #pragma unroll
        for (int tt = 0; tt < 2; ++tt) {
            const f32x16& a = tt ? aS1 : aS0;
            float p[16];
            #pragma unroll
            for (int r = 0; r < 16; r += 2) {
                p[r]     = __builtin_amdgcn_exp2f(a[r] * SCL);
                p[r + 1] = __builtin_amdgcn_exp2f(a[r + 1] * SCL);
                lsp0 += p[r];
                lsp1 += p[r + 1];
            }
            #pragma unroll
            for (int sub = 0; sub < 2; ++sub) {
                union { uint u[4]; bf16x8 v; } cv;
                #pragma unroll
                for (int dd = 0; dd < 4; ++dd)
                    cv.u[dd] = __builtin_amdgcn_perm(
                        __float_as_uint(p[sub * 8 + 2 * dd + 1]),
                        __float_as_uint(p[sub * 8 + 2 * dd]), 0x07060302u);
                af[tt * 2 + sub] = cv.v;
            }
        }

        // ---- O[32 t x 64 s] += P V  (from buf rb KTf, stride-24 slots) ----
        __builtin_amdgcn_s_setprio(1);
        #pragma unroll
        for (int c = 0; c < 4; ++c) {
            bf16x8 v0 = *(bf16x8*)&smem[rb + 4096 + c * 1536 + prow + 0];
            bf16x8 v1 = *(bf16x8*)&smem[rb + 4096 + c * 1536 + prow + 8];
            accO0 = __builtin_amdgcn_mfma_f32_32x32x16_bf16(af[c], v0, accO0, 0, 0, 0);
            accO1 = __builtin_amdgcn_mfma_f32_32x32x16_bf16(af[c], v1, accO1, 0, 0, 0);
        }
        __builtin_amdgcn_s_setprio(0);
        rb = wb;
    }

    // ---- denominators; 1.0039 compensates P truncation bias ----
    float lsp = lsp0 + lsp1;
    float dsum = lsp + __shfl_xor(lsp, 32);
    short* ob = o + (size_t)b * (T_ * D_) + hh * S_;
    #pragma unroll
    for (int r = 0; r < 16; ++r) {
        int rt = (r & 3) + 8 * (r >> 2) + 4 * h32;
        float inv = 1.00390625f / __shfl(dsum, rt);
        size_t t = (size_t)(t0 + wv * 32 + rt);
        ob[t * D_ + (lane & 31)]      = f2bf(accO0[r] * inv);
        ob[t * D_ + 32 + (lane & 31)] = f2bf(accO1[r] * inv);
    }
}

extern "C" void kernel_launch(void* const* d_in, const int* in_sizes, int n_in,
                              void* d_out, int out_size, void* d_ws, size_t ws_size,
                              hipStream_t stream) {
    const float* x  = (const float*)d_in[0];
    const float* Wq = (const float*)d_in[1];
    const float* Wu = (const float*)d_in[2];
    const float* bu = (const float*)d_in[3];
    float* out  = (float*)d_out;
    short* qbuf = (short*)d_out;                          // bf16 q, bytes [0,16.8M)
    short* xb   = (short*)((char*)d_out + 16777216);      // bf16 x, bytes [16.8M,33.5M)
    short* attn = (short*)d_ws;                           // bf16 attn out (16.8 MB)
    short* wqb  = (short*)((char*)d_ws + 16777216);       // bf16 Wq (2 MB)
    short* wub  = (short*)((char*)d_ws + 18874368);       // bf16 Wu (2 MB)

    const int M = B_ * T_;
    dim3 gg(D_ / 128, M / 128);                           // 128x128 tiles: (8,64)
    // 0) bf16 conversions (x, Wq, Wu) in one launch
    hipLaunchKernelGGL(cvt3, dim3(5120), dim3(256), 0, stream, x, Wq, Wu, xb, wqb, wub);
    // 1) q_bf16 = x_bf @ Wq_bf^T
    hipLaunchKernelGGL((gemm_bt<true>), gg, dim3(256), 0, stream,
                       xb, wqb, (const float*)nullptr, (void*)qbuf, M, D_, D_);
    // 2) attn_bf16 = softmax(q q^T / 8) q
    hipLaunchKernelGGL(attn_mfma, dim3(T_ / 128, B_ * H_), dim3(256), 0, stream, qbuf, attn);
    // 3) out = attn @ Wu_bf^T + bu   (fp32)
    hipLaunchKernelGGL((gemm_bt<false>), gg, dim3(256), 0, stream,
                       attn, wub, bu, (void*)out, M, D_, D_);
}

// Round 11
// 223.809 us; speedup vs baseline: 1.0091x; 1.0091x over previous
//
#include <hip/hip_runtime.h>

#define B_ 4
#define T_ 2048
#define D_ 1024
#define H_ 16
#define S_ 64

typedef __attribute__((ext_vector_type(8))) short bf16x8;
typedef __attribute__((ext_vector_type(16))) float f32x16;
typedef unsigned int uint;

__device__ __forceinline__ short f2bf(float f) {
    union { float f; uint u; } v; v.f = f;
    uint r = v.u + 0x7fffu + ((v.u >> 16) & 1u);   // RNE
    return (short)(r >> 16);
}

// async global->LDS, 16B per lane; LDS dst = wave-uniform base + lane*16
__device__ __forceinline__ void gld16(const short* g, short* l) {
    __builtin_amdgcn_global_load_lds((const __attribute__((address_space(1))) void*)g,
                                     (__attribute__((address_space(3))) void*)l, 16, 0, 0);
}

// ---------------- fused fp32->bf16 prepass: x, Wq, Wu ----------------
__global__ __launch_bounds__(256) void cvt3(const float* __restrict__ x,
                                            const float* __restrict__ wq,
                                            const float* __restrict__ wu,
                                            short* __restrict__ xb,
                                            short* __restrict__ wqb,
                                            short* __restrict__ wub) {
    const int NX = B_ * T_ * D_ / 8;   // 1048576 8-elem units
    const int NW = D_ * D_ / 8;        // 131072
    int i = blockIdx.x * 256 + threadIdx.x;
    const float* src; short* dst; int off;
    if (i < NX)            { src = x;  dst = xb;  off = i; }
    else if (i < NX + NW)  { src = wq; dst = wqb; off = i - NX; }
    else                   { src = wu; dst = wub; off = i - NX - NW; }
    float4 a = *(const float4*)(src + (size_t)off * 8);
    float4 b = *(const float4*)(src + (size_t)off * 8 + 4);
    short o[8] = {f2bf(a.x), f2bf(a.y), f2bf(a.z), f2bf(a.w),
                  f2bf(b.x), f2bf(b.y), f2bf(b.z), f2bf(b.w)};
    *(bf16x8*)(dst + (size_t)off * 8) = *(bf16x8*)o;
}

// ---------------- bf16 MFMA GEMM v8 (RESTORED — best measured) --------------
// C[M,N] = A[M,K] @ Bt[N,K]^T (+bias). 128x128 tile, 256 thr (2wm x 2wn,
// wave owns 64x64 = 2x2 f32x16 acc). BK=64, 2 buffers, 1 barrier/step,
// gld16 DMA staging, coalesced (8 lanes x 128B rows) + src-side XOR swizzle.
// r9/r10's reg-staging was -7us vs this (reg tax, no latency win: r8's DMA
// loads were already issued a full compute phase ahead). 9 experiments ->
// structural floor ~286 TF/gemm at 2 blocks/CU; do not re-litigate.
#define STAGE_CO(t, bi) do {                                                      \
        const int kk_ = (t) << 6;                                                 \
        const short* gp_ = (wv < 2) ? Ap : Bp;                                    \
        short* lp_ = (wv < 2) ? &As[bi][0] : &Bs[bi][0];                          \
        const int half_ = wv & 1;                                                 \
        _Pragma("unroll")                                                         \
        for (int c_ = 0; c_ < 8; ++c_) {                                          \
            const int r8_  = half_ * 8 + c_;          /* 8-row group 0..15 */     \
            const int row_ = r8_ * 8 + (lane >> 3);                               \
            const int cs_  = (lane & 7) ^ (lane >> 3); /* pre-swizzled chunk */   \
            gld16(gp_ + (size_t)row_ * K + kk_ + cs_ * 8, lp_ + r8_ * 512);       \
        }                                                                         \
    } while (0)

template <bool OUT_BF16>
__global__ __launch_bounds__(256, 2) void gemm_bt(const short* __restrict__ A,
                                                  const short* __restrict__ Bt,
                                                  const float* __restrict__ bias,
                                                  void* __restrict__ Cv,
                                                  int M, int N, int K) {
    __shared__ short As[2][8192];   // 2 x 16 KB, row-major [128][64] bf16
    __shared__ short Bs[2][8192];   // 2 x 16 KB
    const int tid  = threadIdx.x;
    const int lane = tid & 63;
    const int wv   = tid >> 6;       // 0..3
    const int wm   = wv >> 1;        // 0..1 -> 64-row strip
    const int wn   = wv & 1;         // 0..1 -> 64-col strip
    const int h32  = lane >> 5;

    // bijective XCD swizzle: each XCD owns nby/8 contiguous m-panels x all n.
    int bx = blockIdx.x, by = blockIdx.y;
    {
        const int nbx = gridDim.x, nby = gridDim.y;
        if ((nby & 7) == 0) {
            int f = blockIdx.x + nbx * blockIdx.y;
            int xcd = f & 7, slot = f >> 3;
            bx = slot % nbx;
            by = xcd * (nby >> 3) + slot / nbx;
        }
    }
    const int m0 = by * 128, n0 = bx * 128;
    const short* Ap = A + (size_t)m0 * K;
    const short* Bp = Bt + (size_t)n0 * K;

    f32x16 acc[2][2];
    #pragma unroll
    for (int i = 0; i < 2; ++i)
        #pragma unroll
        for (int j = 0; j < 2; ++j)
            #pragma unroll
            for (int r = 0; r < 16; ++r) acc[i][j][r] = 0.f;

    // fragment-read geometry (rows fixed per lane; slot varies by kk8)
    const int ra0 = wm * 64 + (lane & 31);    // A rows: ra0, ra0+32
    const int rb0 = wn * 64 + (lane & 31);    // B rows: rb0, rb0+32
    const int l7  = lane & 7;                 // == row&7 for all four rows

    const int nt = K >> 6;           // 16 K-steps (K=1024)
    STAGE_CO(0, 0);                  // 8 gld16/wave in flight

    for (int t = 0; t < nt; ++t) {
        const int cur = t & 1;
        asm volatile("s_waitcnt vmcnt(0)" ::: "memory");  // own tile-t chunks landed
        __builtin_amdgcn_s_barrier();                     // everyone's landed; buf^1 free
        asm volatile("" ::: "memory");

        if (t + 1 < nt) STAGE_CO(t + 1, cur ^ 1);         // full compute phase to land

        const short* Ab = As[cur];
        const short* Bb = Bs[cur];
        #pragma unroll
        for (int ks = 0; ks < 4; ++ks) {
            const int kk8 = ks * 2 + h32;
            const int sl  = (kk8 ^ l7) * 8;
            bf16x8 a0 = *(bf16x8*)&Ab[ra0 * 64 + sl];
            bf16x8 a1 = *(bf16x8*)&Ab[(ra0 + 32) * 64 + sl];
            bf16x8 b0 = *(bf16x8*)&Bb[rb0 * 64 + sl];
            bf16x8 b1 = *(bf16x8*)&Bb[(rb0 + 32) * 64 + sl];
            acc[0][0] = __builtin_amdgcn_mfma_f32_32x32x16_bf16(a0, b0, acc[0][0], 0, 0, 0);
            acc[0][1] = __builtin_amdgcn_mfma_f32_32x32x16_bf16(a0, b1, acc[0][1], 0, 0, 0);
            acc[1][0] = __builtin_amdgcn_mfma_f32_32x32x16_bf16(a1, b0, acc[1][0], 0, 0, 0);
            acc[1][1] = __builtin_amdgcn_mfma_f32_32x32x16_bf16(a1, b1, acc[1][1], 0, 0, 0);
        }
    }

    #pragma unroll
    for (int mt = 0; mt < 2; ++mt) {
        #pragma unroll
        for (int nt2 = 0; nt2 < 2; ++nt2) {
            const int rbase = m0 + wm * 64 + mt * 32;
            const int col   = n0 + wn * 64 + nt2 * 32 + (lane & 31);
            float bv = 0.f;
            if (!OUT_BF16 && bias) bv = bias[col];
            #pragma unroll
            for (int r = 0; r < 16; ++r) {
                int row = rbase + (r & 3) + 8 * (r >> 2) + 4 * h32;
                if constexpr (OUT_BF16)
                    ((short*)Cv)[(size_t)row * N + col] = f2bf(acc[mt][nt2][r]);
                else
                    ((float*)Cv)[(size_t)row * N + col] = acc[mt][nt2][r] + bv;
            }
        }
    }
}

// ---------------- MFMA attention v7: denominator via MFMA (ones-column) -----
// v6 structure kept. THE CHANGE: the softmax denominator is computed by the
// matrix pipe instead of the VALU — accD = sum_c mfma(af[c], ones): with an
// all-ones B operand, every output column of D equals the row-sum of P, in
// exactly accO's C-layout, so inv = 1/accD[r] with NO cross-lane shuffles.
// Removes 32 v_add/iter/thread (VALU is the 48%-busy pipe) + the epilogue
// shfl dance, for 4 extra MFMA/iter (the 35%-busy pipe). Numerics improve:
// denominator now sums the SAME truncated-bf16 P as the numerator, so the
// 1.0039 truncation-compensation is removed (consistent ratio).
__global__ __launch_bounds__(256, 3) void attn_mfma(const short* __restrict__ q,
                                                    short* __restrict__ o) {
    __shared__ short smem[20480];   // 40 KB: buf0=[0,10240), buf1=[10240,20480)
    const int tid  = threadIdx.x;
    const int lane = tid & 63;
    const int wv   = tid >> 6;
    const int h32  = lane >> 5;
    const int b  = blockIdx.y >> 4;
    const int hh = blockIdx.y & 15;
    const int t0 = blockIdx.x * 128;
    const short* qb = q + (size_t)b * (T_ * D_) + hh * S_;

    // tile-invariant staging geometry
    const int c8  = tid & 7;
    const int uu0 = tid >> 3;            // 0..31
    const int uu1 = uu0 + 32;            // 32..63
    const int u_0 = (uu0 & 0x33) | ((uu0 & 4) << 1) | ((uu0 & 8) >> 1);  // b2<->b3
    const int u_1 = (uu1 & 0x33) | ((uu1 & 4) << 1) | ((uu1 & 8) >> 1);
    const int kfo0 = (c8 * 64 + (u_0 ^ c8)) * 8;          // Kf within buffer
    const int kfo1 = (c8 * 64 + (u_1 ^ c8)) * 8;
    const int kto0 = 4096 + (u_0 >> 4) * 1536 + ((u_0 >> 2) & 1) * 768 + (c8 >> 2) * 8
                   + ((u_0 & 3) | (((u_0 >> 3) & 1) << 2)) + (c8 & 3) * 24;
    const int kto1 = 4096 + (u_1 >> 4) * 1536 + ((u_1 >> 2) & 1) * 768 + (c8 >> 2) * 8
                   + ((u_1 & 3) | (((u_1 >> 3) & 1) << 2)) + (c8 & 3) * 24;
    const short* g0 = qb + (size_t)u_0 * D_ + c8 * 8;
    const short* g1 = qb + (size_t)u_1 * D_ + c8 * 8;

    // ---- prologue: issue tile-0 loads, stage Q, read Q frags ----
    bf16x8 st0 = *(const bf16x8*)g0;            // tile 0 (u0 = 0)
    bf16x8 st1 = *(const bf16x8*)g1;
    #pragma unroll
    for (int rep = 0; rep < 4; ++rep) {
        int f = rep * 256 + tid;
        int r = f >> 3, cq = f & 7;
        bf16x8 v = *(const bf16x8*)(qb + (size_t)(t0 + r) * D_ + cq * 8);
        *(bf16x8*)&smem[(cq * 128 + (r ^ cq)) * 8] = v;
    }
    __syncthreads();
    bf16x8 Qreg[4];
    #pragma unroll
    for (int ks = 0; ks < 4; ++ks) {
        int kk8 = 2 * ks + h32;
        Qreg[ks] = *(bf16x8*)&smem[(kk8 * 128 + ((wv * 32 + (lane & 31)) ^ kk8)) * 8];
    }
    __syncthreads();                             // Q region (subset of buf0) free now
    // write tile 0 into buf0; issue tile-1 loads
    *(bf16x8*)&smem[kfo0] = st0;
    *(bf16x8*)&smem[kfo1] = st1;
    #pragma unroll
    for (int ds = 0; ds < 8; ++ds) {
        smem[kto0 + ds * 96] = st0[ds];
        smem[kto1 + ds * 96] = st1[ds];
    }
    st0 = *(const bf16x8*)(g0 + (size_t)64 * D_);
    st1 = *(const bf16x8*)(g1 + (size_t)64 * D_);

    // all-ones bf16 B-fragment for the denominator MFMA
    bf16x8 ones;
    #pragma unroll
    for (int i = 0; i < 8; ++i) ones[i] = (short)0x3F80;   // bf16 1.0

    f32x16 accO0, accO1, accD;
    #pragma unroll
    for (int i = 0; i < 16; ++i) { accO0[i] = 0.f; accO1[i] = 0.f; accD[i] = 0.f; }
    const int prow = ((((lane & 7) << 2) | ((lane >> 3) & 3)) * 24) + h32 * 768;
    const float SCL = 0.18033688f;               // 0.125 * log2(e)

    int rb = 0;                                  // read-buffer base (shorts)
    for (int u0 = 0; u0 < T_; u0 += 64) {
        __syncthreads();          // everyone done with prev tile (other buffer)
        const int wb = 10240 - rb;

        // ---- S^T[64 keys x 32 t] = K Q^T  (from buf rb) ----
        f32x16 aS0, aS1;
        #pragma unroll
        for (int i = 0; i < 16; ++i) { aS0[i] = 0.f; aS1[i] = 0.f; }
        __builtin_amdgcn_s_setprio(1);
        #pragma unroll
        for (int ks = 0; ks < 4; ++ks) {
            int kk8 = 2 * ks + h32;
            bf16x8 k0 = *(bf16x8*)&smem[rb + (kk8 * 64 + ((lane & 31) ^ kk8)) * 8];
            bf16x8 k1 = *(bf16x8*)&smem[rb + (kk8 * 64 + ((32 + (lane & 31)) ^ kk8)) * 8];
            aS0 = __builtin_amdgcn_mfma_f32_32x32x16_bf16(k0, Qreg[ks], aS0, 0, 0, 0);
            aS1 = __builtin_amdgcn_mfma_f32_32x32x16_bf16(k1, Qreg[ks], aS1, 0, 0, 0);
        }
        __builtin_amdgcn_s_setprio(0);

        // ---- stage tile u0+64 into buf wb (regs loaded last iter) ----
        *(bf16x8*)&smem[wb + kfo0] = st0;
        *(bf16x8*)&smem[wb + kfo1] = st1;
        #pragma unroll
        for (int ds = 0; ds < 8; ++ds) {
            smem[wb + kto0 + ds * 96] = st0[ds];
            smem[wb + kto1 + ds * 96] = st1[ds];
        }
        // ---- issue loads for tile u0+128 (used next iteration) ----
        int un = u0 + 128; if (un >= T_) un = 0;   // tail: harmless dummy
        st0 = *(const bf16x8*)(g0 + (size_t)un * D_);
        st1 = *(const bf16x8*)(g1 + (size_t)un * D_);

        // ---- exp2; pack C-layout -> A-frags (no lsp adds any more) ----
        bf16x8 af[4];
        #pragma unroll
        for (int tt = 0; tt < 2; ++tt) {
            const f32x16& a = tt ? aS1 : aS0;
            float p[16];
            #pragma unroll
            for (int r = 0; r < 16; ++r)
                p[r] = __builtin_amdgcn_exp2f(a[r] * SCL);
            #pragma unroll
            for (int sub = 0; sub < 2; ++sub) {
                union { uint u[4]; bf16x8 v; } cv;
                #pragma unroll
                for (int dd = 0; dd < 4; ++dd)
                    cv.u[dd] = __builtin_amdgcn_perm(
                        __float_as_uint(p[sub * 8 + 2 * dd + 1]),
                        __float_as_uint(p[sub * 8 + 2 * dd]), 0x07060302u);
                af[tt * 2 + sub] = cv.v;
            }
        }

        // ---- O[32 t x 64 s] += P V ; D[t] += P . 1  (matrix-pipe denom) ----
        __builtin_amdgcn_s_setprio(1);
        #pragma unroll
        for (int c = 0; c < 4; ++c) {
            bf16x8 v0 = *(bf16x8*)&smem[rb + 4096 + c * 1536 + prow + 0];
            bf16x8 v1 = *(bf16x8*)&smem[rb + 4096 + c * 1536 + prow + 8];
            accO0 = __builtin_amdgcn_mfma_f32_32x32x16_bf16(af[c], v0, accO0, 0, 0, 0);
            accO1 = __builtin_amdgcn_mfma_f32_32x32x16_bf16(af[c], v1, accO1, 0, 0, 0);
            accD  = __builtin_amdgcn_mfma_f32_32x32x16_bf16(af[c], ones, accD, 0, 0, 0);
        }
        __builtin_amdgcn_s_setprio(0);
        rb = wb;
    }

    // ---- epilogue: inv directly from accD (same C-layout row as accO) ----
    short* ob = o + (size_t)b * (T_ * D_) + hh * S_;
    #pragma unroll
    for (int r = 0; r < 16; ++r) {
        int rt = (r & 3) + 8 * (r >> 2) + 4 * h32;
        float inv = 1.0f / accD[r];
        size_t t = (size_t)(t0 + wv * 32 + rt);
        ob[t * D_ + (lane & 31)]      = f2bf(accO0[r] * inv);
        ob[t * D_ + 32 + (lane & 31)] = f2bf(accO1[r] * inv);
    }
}

extern "C" void kernel_launch(void* const* d_in, const int* in_sizes, int n_in,
                              void* d_out, int out_size, void* d_ws, size_t ws_size,
                              hipStream_t stream) {
    const float* x  = (const float*)d_in[0];
    const float* Wq = (const float*)d_in[1];
    const float* Wu = (const float*)d_in[2];
    const float* bu = (const float*)d_in[3];
    float* out  = (float*)d_out;
    short* qbuf = (short*)d_out;                          // bf16 q, bytes [0,16.8M)
    short* xb   = (short*)((char*)d_out + 16777216);      // bf16 x, bytes [16.8M,33.5M)
    short* attn = (short*)d_ws;                           // bf16 attn out (16.8 MB)
    short* wqb  = (short*)((char*)d_ws + 16777216);       // bf16 Wq (2 MB)
    short* wub  = (short*)((char*)d_ws + 18874368);       // bf16 Wu (2 MB)

    const int M = B_ * T_;
    dim3 gg(D_ / 128, M / 128);                           // 128x128 tiles: (8,64)
    // 0) bf16 conversions (x, Wq, Wu) in one launch
    hipLaunchKernelGGL(cvt3, dim3(5120), dim3(256), 0, stream, x, Wq, Wu, xb, wqb, wub);
    // 1) q_bf16 = x_bf @ Wq_bf^T
    hipLaunchKernelGGL((gemm_bt<true>), gg, dim3(256), 0, stream,
                       xb, wqb, (const float*)nullptr, (void*)qbuf, M, D_, D_);
    // 2) attn_bf16 = softmax(q q^T / 8) q
    hipLaunchKernelGGL(attn_mfma, dim3(T_ / 128, B_ * H_), dim3(256), 0, stream, qbuf, attn);
    // 3) out = attn @ Wu_bf^T + bu   (fp32)
    hipLaunchKernelGGL((gemm_bt<false>), gg, dim3(256), 0, stream,
                       attn, wub, bu, (void*)out, M, D_, D_);
}

// Round 12
// 210.770 us; speedup vs baseline: 1.0716x; 1.0619x over previous
//
#include <hip/hip_runtime.h>

#define B_ 4
#define T_ 2048
#define D_ 1024
#define H_ 16
#define S_ 64

typedef __attribute__((ext_vector_type(8))) short bf16x8;
typedef __attribute__((ext_vector_type(16))) float f32x16;
typedef unsigned int uint;

__device__ __forceinline__ short f2bf(float f) {
    union { float f; uint u; } v; v.f = f;
    uint r = v.u + 0x7fffu + ((v.u >> 16) & 1u);   // RNE
    return (short)(r >> 16);
}

// async global->LDS, 16B per lane; LDS dst = wave-uniform base + lane*16
__device__ __forceinline__ void gld16(const short* g, short* l) {
    __builtin_amdgcn_global_load_lds((const __attribute__((address_space(1))) void*)g,
                                     (__attribute__((address_space(3))) void*)l, 16, 0, 0);
}

// ---------------- fused fp32->bf16 prepass: x, Wq, Wu ----------------
__global__ __launch_bounds__(256) void cvt3(const float* __restrict__ x,
                                            const float* __restrict__ wq,
                                            const float* __restrict__ wu,
                                            short* __restrict__ xb,
                                            short* __restrict__ wqb,
                                            short* __restrict__ wub) {
    const int NX = B_ * T_ * D_ / 8;   // 1048576 8-elem units
    const int NW = D_ * D_ / 8;        // 131072
    int i = blockIdx.x * 256 + threadIdx.x;
    const float* src; short* dst; int off;
    if (i < NX)            { src = x;  dst = xb;  off = i; }
    else if (i < NX + NW)  { src = wq; dst = wqb; off = i - NX; }
    else                   { src = wu; dst = wub; off = i - NX - NW; }
    float4 a = *(const float4*)(src + (size_t)off * 8);
    float4 b = *(const float4*)(src + (size_t)off * 8 + 4);
    short o[8] = {f2bf(a.x), f2bf(a.y), f2bf(a.z), f2bf(a.w),
                  f2bf(b.x), f2bf(b.y), f2bf(b.z), f2bf(b.w)};
    *(bf16x8*)(dst + (size_t)off * 8) = *(bf16x8*)o;
}

// ---------------- bf16 MFMA GEMM v8 (best measured; declared floor) ---------
// C[M,N] = A[M,K] @ Bt[N,K]^T (+bias). 128x128 tile, 256 thr (2wm x 2wn,
// wave owns 64x64 = 2x2 f32x16 acc). BK=64, 2 buffers, 1 barrier/step,
// gld16 DMA staging, coalesced (8 lanes x 128B rows) + src-side XOR swizzle.
#define STAGE_CO(t, bi) do {                                                      \
        const int kk_ = (t) << 6;                                                 \
        const short* gp_ = (wv < 2) ? Ap : Bp;                                    \
        short* lp_ = (wv < 2) ? &As[bi][0] : &Bs[bi][0];                          \
        const int half_ = wv & 1;                                                 \
        _Pragma("unroll")                                                         \
        for (int c_ = 0; c_ < 8; ++c_) {                                          \
            const int r8_  = half_ * 8 + c_;          /* 8-row group 0..15 */     \
            const int row_ = r8_ * 8 + (lane >> 3);                               \
            const int cs_  = (lane & 7) ^ (lane >> 3); /* pre-swizzled chunk */   \
            gld16(gp_ + (size_t)row_ * K + kk_ + cs_ * 8, lp_ + r8_ * 512);       \
        }                                                                         \
    } while (0)

template <bool OUT_BF16>
__global__ __launch_bounds__(256, 2) void gemm_bt(const short* __restrict__ A,
                                                  const short* __restrict__ Bt,
                                                  const float* __restrict__ bias,
                                                  void* __restrict__ Cv,
                                                  int M, int N, int K) {
    __shared__ short As[2][8192];   // 2 x 16 KB, row-major [128][64] bf16
    __shared__ short Bs[2][8192];   // 2 x 16 KB
    const int tid  = threadIdx.x;
    const int lane = tid & 63;
    const int wv   = tid >> 6;       // 0..3
    const int wm   = wv >> 1;        // 0..1 -> 64-row strip
    const int wn   = wv & 1;         // 0..1 -> 64-col strip
    const int h32  = lane >> 5;

    // bijective XCD swizzle: each XCD owns nby/8 contiguous m-panels x all n.
    int bx = blockIdx.x, by = blockIdx.y;
    {
        const int nbx = gridDim.x, nby = gridDim.y;
        if ((nby & 7) == 0) {
            int f = blockIdx.x + nbx * blockIdx.y;
            int xcd = f & 7, slot = f >> 3;
            bx = slot % nbx;
            by = xcd * (nby >> 3) + slot / nbx;
        }
    }
    const int m0 = by * 128, n0 = bx * 128;
    const short* Ap = A + (size_t)m0 * K;
    const short* Bp = Bt + (size_t)n0 * K;

    f32x16 acc[2][2];
    #pragma unroll
    for (int i = 0; i < 2; ++i)
        #pragma unroll
        for (int j = 0; j < 2; ++j)
            #pragma unroll
            for (int r = 0; r < 16; ++r) acc[i][j][r] = 0.f;

    // fragment-read geometry (rows fixed per lane; slot varies by kk8)
    const int ra0 = wm * 64 + (lane & 31);    // A rows: ra0, ra0+32
    const int rb0 = wn * 64 + (lane & 31);    // B rows: rb0, rb0+32
    const int l7  = lane & 7;                 // == row&7 for all four rows

    const int nt = K >> 6;           // 16 K-steps (K=1024)
    STAGE_CO(0, 0);                  // 8 gld16/wave in flight

    for (int t = 0; t < nt; ++t) {
        const int cur = t & 1;
        asm volatile("s_waitcnt vmcnt(0)" ::: "memory");  // own tile-t chunks landed
        __builtin_amdgcn_s_barrier();                     // everyone's landed; buf^1 free
        asm volatile("" ::: "memory");

        if (t + 1 < nt) STAGE_CO(t + 1, cur ^ 1);         // full compute phase to land

        const short* Ab = As[cur];
        const short* Bb = Bs[cur];
        #pragma unroll
        for (int ks = 0; ks < 4; ++ks) {
            const int kk8 = ks * 2 + h32;
            const int sl  = (kk8 ^ l7) * 8;
            bf16x8 a0 = *(bf16x8*)&Ab[ra0 * 64 + sl];
            bf16x8 a1 = *(bf16x8*)&Ab[(ra0 + 32) * 64 + sl];
            bf16x8 b0 = *(bf16x8*)&Bb[rb0 * 64 + sl];
            bf16x8 b1 = *(bf16x8*)&Bb[(rb0 + 32) * 64 + sl];
            acc[0][0] = __builtin_amdgcn_mfma_f32_32x32x16_bf16(a0, b0, acc[0][0], 0, 0, 0);
            acc[0][1] = __builtin_amdgcn_mfma_f32_32x32x16_bf16(a0, b1, acc[0][1], 0, 0, 0);
            acc[1][0] = __builtin_amdgcn_mfma_f32_32x32x16_bf16(a1, b0, acc[1][0], 0, 0, 0);
            acc[1][1] = __builtin_amdgcn_mfma_f32_32x32x16_bf16(a1, b1, acc[1][1], 0, 0, 0);
        }
    }

    #pragma unroll
    for (int mt = 0; mt < 2; ++mt) {
        #pragma unroll
        for (int nt2 = 0; nt2 < 2; ++nt2) {
            const int rbase = m0 + wm * 64 + mt * 32;
            const int col   = n0 + wn * 64 + nt2 * 32 + (lane & 31);
            float bv = 0.f;
            if (!OUT_BF16 && bias) bv = bias[col];
            #pragma unroll
            for (int r = 0; r < 16; ++r) {
                int row = rbase + (r & 3) + 8 * (r >> 2) + 4 * h32;
                if constexpr (OUT_BF16)
                    ((short*)Cv)[(size_t)row * N + col] = f2bf(acc[mt][nt2][r]);
                else
                    ((float*)Cv)[(size_t)row * N + col] = acc[mt][nt2][r] + bv;
            }
        }
    }
}

// ---------------- MFMA attention v8: v6 base + Q-prescale -------------------
// v6 structure restored (lsp VALU denom, VGPR 64, occupancy ~31% — v7's
// ones-denom cost 16 VGPR -> occupancy 23%, net neutral). THE CHANGE:
// SCL = 0.125*log2e is folded into the Q fragments ONCE at the prologue
// (unpack bf16 -> f32 mul -> RNE repack), so the inner loop computes
// p = exp2(aS[r]) directly — removing 32 v_mul_f32 per iter per thread
// from the 44-49%-busy VALU pipe at ZERO register cost.
__global__ __launch_bounds__(256, 3) void attn_mfma(const short* __restrict__ q,
                                                    short* __restrict__ o) {
    __shared__ short smem[20480];   // 40 KB: buf0=[0,10240), buf1=[10240,20480)
    const int tid  = threadIdx.x;
    const int lane = tid & 63;
    const int wv   = tid >> 6;
    const int h32  = lane >> 5;
    const int b  = blockIdx.y >> 4;
    const int hh = blockIdx.y & 15;
    const int t0 = blockIdx.x * 128;
    const short* qb = q + (size_t)b * (T_ * D_) + hh * S_;
    const float SCL = 0.18033688f;               // 0.125 * log2(e)

    // tile-invariant staging geometry
    const int c8  = tid & 7;
    const int uu0 = tid >> 3;            // 0..31
    const int uu1 = uu0 + 32;            // 32..63
    const int u_0 = (uu0 & 0x33) | ((uu0 & 4) << 1) | ((uu0 & 8) >> 1);  // b2<->b3
    const int u_1 = (uu1 & 0x33) | ((uu1 & 4) << 1) | ((uu1 & 8) >> 1);
    const int kfo0 = (c8 * 64 + (u_0 ^ c8)) * 8;          // Kf within buffer
    const int kfo1 = (c8 * 64 + (u_1 ^ c8)) * 8;
    const int kto0 = 4096 + (u_0 >> 4) * 1536 + ((u_0 >> 2) & 1) * 768 + (c8 >> 2) * 8
                   + ((u_0 & 3) | (((u_0 >> 3) & 1) << 2)) + (c8 & 3) * 24;
    const int kto1 = 4096 + (u_1 >> 4) * 1536 + ((u_1 >> 2) & 1) * 768 + (c8 >> 2) * 8
                   + ((u_1 & 3) | (((u_1 >> 3) & 1) << 2)) + (c8 & 3) * 24;
    const short* g0 = qb + (size_t)u_0 * D_ + c8 * 8;
    const short* g1 = qb + (size_t)u_1 * D_ + c8 * 8;

    // ---- prologue: issue tile-0 loads, stage Q, read + PRESCALE Q frags ----
    bf16x8 st0 = *(const bf16x8*)g0;            // tile 0 (u0 = 0)
    bf16x8 st1 = *(const bf16x8*)g1;
    #pragma unroll
    for (int rep = 0; rep < 4; ++rep) {
        int f = rep * 256 + tid;
        int r = f >> 3, cq = f & 7;
        bf16x8 v = *(const bf16x8*)(qb + (size_t)(t0 + r) * D_ + cq * 8);
        *(bf16x8*)&smem[(cq * 128 + (r ^ cq)) * 8] = v;
    }
    __syncthreads();
    bf16x8 Qreg[4];
    #pragma unroll
    for (int ks = 0; ks < 4; ++ks) {
        int kk8 = 2 * ks + h32;
        bf16x8 qv = *(bf16x8*)&smem[(kk8 * 128 + ((wv * 32 + (lane & 31)) ^ kk8)) * 8];
        #pragma unroll
        for (int i = 0; i < 8; ++i) {
            float qf = __uint_as_float(((uint)(unsigned short)qv[i]) << 16);
            qv[i] = f2bf(qf * SCL);
        }
        Qreg[ks] = qv;
    }
    __syncthreads();                             // Q region (subset of buf0) free now
    // write tile 0 into buf0; issue tile-1 loads
    *(bf16x8*)&smem[kfo0] = st0;
    *(bf16x8*)&smem[kfo1] = st1;
    #pragma unroll
    for (int ds = 0; ds < 8; ++ds) {
        smem[kto0 + ds * 96] = st0[ds];
        smem[kto1 + ds * 96] = st1[ds];
    }
    st0 = *(const bf16x8*)(g0 + (size_t)64 * D_);
    st1 = *(const bf16x8*)(g1 + (size_t)64 * D_);

    f32x16 accO0, accO1;
    #pragma unroll
    for (int i = 0; i < 16; ++i) { accO0[i] = 0.f; accO1[i] = 0.f; }
    float lsp0 = 0.f, lsp1 = 0.f;
    const int prow = ((((lane & 7) << 2) | ((lane >> 3) & 3)) * 24) + h32 * 768;

    int rb = 0;                                  // read-buffer base (shorts)
    for (int u0 = 0; u0 < T_; u0 += 64) {
        __syncthreads();          // everyone done with prev tile (other buffer)
        const int wb = 10240 - rb;

        // ---- S^T[64 keys x 32 t] = K (Q*SCL)^T  (from buf rb) ----
        f32x16 aS0, aS1;
        #pragma unroll
        for (int i = 0; i < 16; ++i) { aS0[i] = 0.f; aS1[i] = 0.f; }
        __builtin_amdgcn_s_setprio(1);
        #pragma unroll
        for (int ks = 0; ks < 4; ++ks) {
            int kk8 = 2 * ks + h32;
            bf16x8 k0 = *(bf16x8*)&smem[rb + (kk8 * 64 + ((lane & 31) ^ kk8)) * 8];
            bf16x8 k1 = *(bf16x8*)&smem[rb + (kk8 * 64 + ((32 + (lane & 31)) ^ kk8)) * 8];
            aS0 = __builtin_amdgcn_mfma_f32_32x32x16_bf16(k0, Qreg[ks], aS0, 0, 0, 0);
            aS1 = __builtin_amdgcn_mfma_f32_32x32x16_bf16(k1, Qreg[ks], aS1, 0, 0, 0);
        }
        __builtin_amdgcn_s_setprio(0);

        // ---- stage tile u0+64 into buf wb (regs loaded last iter) ----
        *(bf16x8*)&smem[wb + kfo0] = st0;
        *(bf16x8*)&smem[wb + kfo1] = st1;
        #pragma unroll
        for (int ds = 0; ds < 8; ++ds) {
            smem[wb + kto0 + ds * 96] = st0[ds];
            smem[wb + kto1 + ds * 96] = st1[ds];
        }
        // ---- issue loads for tile u0+128 (used next iteration) ----
        int un = u0 + 128; if (un >= T_) un = 0;   // tail: harmless dummy
        st0 = *(const bf16x8*)(g0 + (size_t)un * D_);
        st1 = *(const bf16x8*)(g1 + (size_t)un * D_);

        // ---- exp2 (no per-element mul); pack C-layout -> A-frags ----
        bf16x8 af[4];
        #pragma unroll
        for (int tt = 0; tt < 2; ++tt) {
            const f32x16& a = tt ? aS1 : aS0;
            float p[16];
            #pragma unroll
            for (int r = 0; r < 16; r += 2) {
                p[r]     = __builtin_amdgcn_exp2f(a[r]);
                p[r + 1] = __builtin_amdgcn_exp2f(a[r + 1]);
                lsp0 += p[r];
                lsp1 += p[r + 1];
            }
            #pragma unroll
            for (int sub = 0; sub < 2; ++sub) {
                union { uint u[4]; bf16x8 v; } cv;
                #pragma unroll
                for (int dd = 0; dd < 4; ++dd)
                    cv.u[dd] = __builtin_amdgcn_perm(
                        __float_as_uint(p[sub * 8 + 2 * dd + 1]),
                        __float_as_uint(p[sub * 8 + 2 * dd]), 0x07060302u);
                af[tt * 2 + sub] = cv.v;
            }
        }

        // ---- O[32 t x 64 s] += P V  (from buf rb KTf, stride-24 slots) ----
        __builtin_amdgcn_s_setprio(1);
        #pragma unroll
        for (int c = 0; c < 4; ++c) {
            bf16x8 v0 = *(bf16x8*)&smem[rb + 4096 + c * 1536 + prow + 0];
            bf16x8 v1 = *(bf16x8*)&smem[rb + 4096 + c * 1536 + prow + 8];
            accO0 = __builtin_amdgcn_mfma_f32_32x32x16_bf16(af[c], v0, accO0, 0, 0, 0);
            accO1 = __builtin_amdgcn_mfma_f32_32x32x16_bf16(af[c], v1, accO1, 0, 0, 0);
        }
        __builtin_amdgcn_s_setprio(0);
        rb = wb;
    }

    // ---- denominators; 1.0039 compensates P truncation bias ----
    float lsp = lsp0 + lsp1;
    float dsum = lsp + __shfl_xor(lsp, 32);
    short* ob = o + (size_t)b * (T_ * D_) + hh * S_;
    #pragma unroll
    for (int r = 0; r < 16; ++r) {
        int rt = (r & 3) + 8 * (r >> 2) + 4 * h32;
        float inv = 1.00390625f / __shfl(dsum, rt);
        size_t t = (size_t)(t0 + wv * 32 + rt);
        ob[t * D_ + (lane & 31)]      = f2bf(accO0[r] * inv);
        ob[t * D_ + 32 + (lane & 31)] = f2bf(accO1[r] * inv);
    }
}

extern "C" void kernel_launch(void* const* d_in, const int* in_sizes, int n_in,
                              void* d_out, int out_size, void* d_ws, size_t ws_size,
                              hipStream_t stream) {
    const float* x  = (const float*)d_in[0];
    const float* Wq = (const float*)d_in[1];
    const float* Wu = (const float*)d_in[2];
    const float* bu = (const float*)d_in[3];
    float* out  = (float*)d_out;
    short* qbuf = (short*)d_out;                          // bf16 q, bytes [0,16.8M)
    short* xb   = (short*)((char*)d_out + 16777216);      // bf16 x, bytes [16.8M,33.5M)
    short* attn = (short*)d_ws;                           // bf16 attn out (16.8 MB)
    short* wqb  = (short*)((char*)d_ws + 16777216);       // bf16 Wq (2 MB)
    short* wub  = (short*)((char*)d_ws + 18874368);       // bf16 Wu (2 MB)

    const int M = B_ * T_;
    dim3 gg(D_ / 128, M / 128);                           // 128x128 tiles: (8,64)
    // 0) bf16 conversions (x, Wq, Wu) in one launch
    hipLaunchKernelGGL(cvt3, dim3(5120), dim3(256), 0, stream, x, Wq, Wu, xb, wqb, wub);
    // 1) q_bf16 = x_bf @ Wq_bf^T
    hipLaunchKernelGGL((gemm_bt<true>), gg, dim3(256), 0, stream,
                       xb, wqb, (const float*)nullptr, (void*)qbuf, M, D_, D_);
    // 2) attn_bf16 = softmax(q q^T / 8) q
    hipLaunchKernelGGL(attn_mfma, dim3(T_ / 128, B_ * H_), dim3(256), 0, stream, qbuf, attn);
    // 3) out = attn @ Wu_bf^T + bu   (fp32)
    hipLaunchKernelGGL((gemm_bt<false>), gg, dim3(256), 0, stream,
                       attn, wub, bu, (void*)out, M, D_, D_);
}